// Round 4
// baseline (180.928 us; speedup 1.0000x reference)
//
#include <hip/hip_runtime.h>
#include <hip/hip_bf16.h>
#include <math.h>

#define S_LEN 2048
#define DIM   1024
#define NH    16
#define NL    4
#define NB    2
#define NPART_BH 40   // sum over 16 q-tiles(128) of ceil((2t+2)/8)
#define SCALE2 0.18033688011f   // 0.125 * log2(e) -> softmax in exp2 domain

typedef __attribute__((ext_vector_type(8))) short bf16x8;
typedef __attribute__((ext_vector_type(4))) float f32x4;
typedef unsigned short u16;

__device__ __forceinline__ float bf2f(u16 u) {
  union { unsigned int i; float f; } x; x.i = ((unsigned int)u) << 16; return x.f;
}
__device__ __forceinline__ u16 f2bf(float f) {  // RNE
  union { float f; unsigned int i; } x; x.f = f;
  unsigned int r = x.i + 0x7fffu + ((x.i >> 16) & 1u);
  return (u16)(r >> 16);
}

__device__ __forceinline__ void g2l16(const void* g, void* l) {
  __builtin_amdgcn_global_load_lds(
      (const __attribute__((address_space(1))) void*)g,
      (__attribute__((address_space(3))) void*)l, 16, 0, 0);
}

// DPP 16-lane butterfly reduce (VALU-speed).
template <int CTRL>
__device__ __forceinline__ float dppf(float x) {
  union { float f; int i; } u, r;
  u.f = x;
  r.i = __builtin_amdgcn_update_dpp(0, u.i, CTRL, 0xF, 0xF, true);
  return r.f;
}
__device__ __forceinline__ float rmax16(float x) {
  x = fmaxf(x, dppf<0xB1>(x));
  x = fmaxf(x, dppf<0x4E>(x));
  x = fmaxf(x, dppf<0x141>(x));
  x = fmaxf(x, dppf<0x140>(x));
  return x;
}
__device__ __forceinline__ float rsum16(float x) {
  x += dppf<0xB1>(x);
  x += dppf<0x4E>(x);
  x += dppf<0x141>(x);
  x += dppf<0x140>(x);
  return x;
}

__global__ void cvt_f32_bf16(const float* __restrict__ in, u16* __restrict__ out, int n4) {
  int i = blockIdx.x * blockDim.x + threadIdx.x;
  if (i >= n4) return;
  float4 v = ((const float4*)in)[i];
  ushort4 o;
  o.x = f2bf(v.x); o.y = f2bf(v.y); o.z = f2bf(v.z); o.w = f2bf(v.w);
  ((ushort4*)out)[i] = o;
}

// C = act(A @ Bt^T + bias). 128x128 tile, BK=64, 4 waves (2x2).
template <bool GELU, typename OT>
__global__ __launch_bounds__(256)
void gemm_bt(const u16* __restrict__ A, const u16* __restrict__ Bt,
             const float* __restrict__ bias, OT* __restrict__ C,
             int M, int N, int K) {
  __shared__ u16 As[128 * 64];
  __shared__ u16 Bs[128 * 64];
  const int lane = threadIdx.x & 63, wave = threadIdx.x >> 6;
  const int ln = lane & 15, g = lane >> 4;
  const int m0 = blockIdx.y * 128, n0 = blockIdx.x * 128;
  const int wm = wave >> 1, wn = wave & 1;
  f32x4 acc[4][4] = {};

  for (int k0 = 0; k0 < K; k0 += 64) {
    __syncthreads();
#pragma unroll
    for (int rd = 0; rd < 4; ++rd) {
      int chunk = rd * 4 + wave;
      int flat = chunk * 1024 + lane * 16;
      int row = flat >> 7;
      int within = (flat & 127) ^ ((row & 7) << 4);
      g2l16((const char*)A + ((size_t)(m0 + row) * K + k0) * 2 + within,
            (char*)As + chunk * 1024);
      g2l16((const char*)Bt + ((size_t)(n0 + row) * K + k0) * 2 + within,
            (char*)Bs + chunk * 1024);
    }
    __syncthreads();
#pragma unroll
    for (int kc = 0; kc < 2; ++kc) {
      bf16x8 af[4], bfr[4];
#pragma unroll
      for (int i = 0; i < 4; ++i) {
        int ra = wm * 64 + i * 16 + ln;
        af[i] = *(const bf16x8*)((const char*)As + ra * 128 +
                                 ((kc * 64 + g * 16) ^ ((ra & 7) << 4)));
        int rb = wn * 64 + i * 16 + ln;
        bfr[i] = *(const bf16x8*)((const char*)Bs + rb * 128 +
                                  ((kc * 64 + g * 16) ^ ((rb & 7) << 4)));
      }
#pragma unroll
      for (int i = 0; i < 4; ++i)
#pragma unroll
        for (int j = 0; j < 4; ++j)
          acc[i][j] = __builtin_amdgcn_mfma_f32_16x16x32_bf16(af[i], bfr[j], acc[i][j], 0, 0, 0);
    }
  }

#pragma unroll
  for (int j = 0; j < 4; ++j) {
    int gc = n0 + wn * 64 + j * 16 + ln;
    float bv = bias[gc];
#pragma unroll
    for (int i = 0; i < 4; ++i) {
      int gr0 = m0 + wm * 64 + i * 16 + g * 4;
#pragma unroll
      for (int r = 0; r < 4; ++r) {
        float v = acc[i][j][r] + bv;
        if constexpr (GELU) v = 0.5f * v * (1.0f + erff(v * 0.70710678118f));
        if constexpr (sizeof(OT) == 2) C[(size_t)(gr0 + r) * N + gc] = (OT)f2bf(v);
        else                           C[(size_t)(gr0 + r) * N + gc] = (OT)v;
      }
    }
  }
}

// Flash self-attention, token part, K-chunked. QBLK=128 (4 waves x 32 q-rows),
// KVBLK=64, double-buffered staging, conflict-free swizzles, exp2-domain
// softmax, bf16 partials. grid (NPART_BH, H, B).
__global__ __launch_bounds__(256)
void attn(const u16* __restrict__ Q, const u16* __restrict__ Xb,
          u16* __restrict__ CTXP, float* __restrict__ MP, float* __restrict__ LP) {
  __shared__ u16 Ks[2][64 * 64];
  __shared__ u16 Vt[2][64 * 64];
  __shared__ u16 Pw[4][32 * 64];

  const int lane = threadIdx.x & 63, wave = threadIdx.x >> 6;
  const int ln = lane & 15, g = lane >> 4;
  const int h = blockIdx.y, b = blockIdx.z;

  // part -> (q-tile t of 128 rows, key-chunk)
  const int p = blockIdx.x;
  int t, chunk;
  if (p < 4)       { t = p;                          chunk = 0; }
  else if (p < 12) { int i = p - 4;  t = 4 + (i >> 1);  chunk = i & 1; }
  else if (p < 24) { int i = p - 12; t = 8 + i / 3;     chunk = i % 3; }
  else             { int i = p - 24; t = 12 + (i >> 2); chunk = i & 3; }
  const int kt0 = chunk * 8;
  const int ktmax = 2 * t + 2;
  const int kt1e = kt0 + 8 < ktmax ? kt0 + 8 : ktmax;

  // Q fragments: 2 q-subtiles of 16 rows per wave
  bf16x8 qa[2][2];
#pragma unroll
  for (int qs = 0; qs < 2; ++qs) {
    const size_t qrow = (size_t)b * S_LEN + t * 128 + wave * 32 + qs * 16 + ln;
#pragma unroll
    for (int kc = 0; kc < 2; ++kc)
      qa[qs][kc] = *(const bf16x8*)(Q + qrow * DIM + h * 64 + kc * 32 + g * 8);
  }

  f32x4 acc[2][4] = {};
  float m_run[2][4], l_run[2][4];
#pragma unroll
  for (int qs = 0; qs < 2; ++qs)
#pragma unroll
    for (int r = 0; r < 4; ++r) { m_run[qs][r] = -INFINITY; l_run[qs][r] = 0.f; }

  const int tid = threadIdx.x;
  const int vr0 = (tid >> 3) * 2;   // key row pair
  const int vc0 = (tid & 7) * 8;    // dim cols
  // conflict-free V^T swizzle: depends on lane-varying bits of c on both sides
#define VSWZ(c) ((((c) ^ ((c) >> 3)) & 7) << 4)

  // prologue: stage tile kt0 into buffer 0
  {
    const u16* xsrc = Xb + ((size_t)b * S_LEN + kt0 * 64 + vr0) * DIM + h * 64 + vc0;
    bf16x8 r0 = *(const bf16x8*)xsrc;
    bf16x8 r1 = *(const bf16x8*)(xsrc + DIM);
#pragma unroll
    for (int rd = 0; rd < 2; ++rd) {
      int ch = rd * 4 + wave;
      int flat = ch * 1024 + lane * 16;
      int row = flat >> 7;
      int within = (flat & 127) ^ ((row & 7) << 4);
      g2l16((const char*)Q + (((size_t)b * S_LEN + kt0 * 64 + row) * DIM + h * 64) * 2 + within,
            (char*)Ks[0] + ch * 1024);
    }
#pragma unroll
    for (int j = 0; j < 8; ++j) {
      int c = vc0 + j;
      unsigned int pack = (unsigned int)(u16)r0[j] | ((unsigned int)(u16)r1[j] << 16);
      *(unsigned int*)((char*)Vt[0] + c * 128 + ((vr0 * 2) ^ VSWZ(c))) = pack;
    }
  }
  __syncthreads();

  for (int kt = kt0; kt < kt1e; ++kt) {
    const int cur = (kt - kt0) & 1, nxt = cur ^ 1;
    const bool more = (kt + 1 < kt1e);
    bf16x8 nr0, nr1;
    if (more) {
      const u16* xsrc = Xb + ((size_t)b * S_LEN + (kt + 1) * 64 + vr0) * DIM + h * 64 + vc0;
      nr0 = *(const bf16x8*)xsrc;
      nr1 = *(const bf16x8*)(xsrc + DIM);
#pragma unroll
      for (int rd = 0; rd < 2; ++rd) {
        int ch = rd * 4 + wave;
        int flat = ch * 1024 + lane * 16;
        int row = flat >> 7;
        int within = (flat & 127) ^ ((row & 7) << 4);
        g2l16((const char*)Q + (((size_t)b * S_LEN + (kt + 1) * 64 + row) * DIM + h * 64) * 2 + within,
              (char*)Ks[nxt] + ch * 1024);
      }
      __builtin_amdgcn_sched_barrier(0);
    }

    // QK^T for both q-subtiles, K fragments read once
    float pq_[2][4][4];
#pragma unroll
    for (int sub = 0; sub < 4; ++sub) {
      int kr = sub * 16 + ln;
      bf16x8 kb0 = *(const bf16x8*)((const char*)Ks[cur] + kr * 128 + ((g * 16) ^ ((kr & 7) << 4)));
      bf16x8 kb1 = *(const bf16x8*)((const char*)Ks[cur] + kr * 128 + ((64 + g * 16) ^ ((kr & 7) << 4)));
#pragma unroll
      for (int qs = 0; qs < 2; ++qs) {
        f32x4 c = {};
        c = __builtin_amdgcn_mfma_f32_16x16x32_bf16(qa[qs][0], kb0, c, 0, 0, 0);
        c = __builtin_amdgcn_mfma_f32_16x16x32_bf16(qa[qs][1], kb1, c, 0, 0, 0);
#pragma unroll
        for (int r = 0; r < 4; ++r) pq_[qs][sub][r] = c[r] * SCALE2;
      }
    }

#pragma unroll
    for (int qs = 0; qs < 2; ++qs) {
      const int s0q = t * 128 + wave * 32 + qs * 16;
      if (kt * 64 > s0q + 15) continue;          // fully-masked subtile: skip
      const bool diag = (kt * 64 + 63 > s0q);
      if (diag) {
#pragma unroll
        for (int sub = 0; sub < 4; ++sub)
#pragma unroll
          for (int r = 0; r < 4; ++r) {
            int key = kt * 64 + sub * 16 + ln;
            int qi = s0q + g * 4 + r;
            if (key > qi) pq_[qs][sub][r] = -INFINITY;
          }
      }
      // online softmax (exp2 domain), rows in 16-lane groups
      float scl[4];
#pragma unroll
      for (int r = 0; r < 4; ++r) {
        float tmax = rmax16(fmaxf(fmaxf(pq_[qs][0][r], pq_[qs][1][r]),
                                  fmaxf(pq_[qs][2][r], pq_[qs][3][r])));
        float mn = fmaxf(m_run[qs][r], tmax);
        scl[r] = exp2f(m_run[qs][r] - mn);
        m_run[qs][r] = mn;
      }
#pragma unroll
      for (int sub = 0; sub < 4; ++sub)
#pragma unroll
        for (int r = 0; r < 4; ++r) pq_[qs][sub][r] = exp2f(pq_[qs][sub][r] - m_run[qs][r]);
#pragma unroll
      for (int r = 0; r < 4; ++r) {
        float su = rsum16(pq_[qs][0][r] + pq_[qs][1][r] + pq_[qs][2][r] + pq_[qs][3][r]);
        l_run[qs][r] = l_run[qs][r] * scl[r] + su;
      }
#pragma unroll
      for (int ns = 0; ns < 4; ++ns)
#pragma unroll
        for (int r = 0; r < 4; ++r) acc[qs][ns][r] *= scl[r];

      // P: C-layout -> LDS (per-wave) -> A-layout
#pragma unroll
      for (int sub = 0; sub < 4; ++sub)
#pragma unroll
        for (int r = 0; r < 4; ++r) {
          int pr = qs * 16 + g * 4 + r;
          *(u16*)((char*)Pw[wave] + pr * 128 + (((sub * 16 + ln) * 2) ^ ((pr & 7) << 4))) =
              f2bf(pq_[qs][sub][r]);
        }
    }

    // PV for both q-subtiles, V fragments read once
    bf16x8 pa[2][2];
#pragma unroll
    for (int qs = 0; qs < 2; ++qs) {
      int prr = qs * 16 + ln;
      pa[qs][0] = *(const bf16x8*)((const char*)Pw[wave] + prr * 128 + ((g * 16) ^ ((ln & 7) << 4)));
      pa[qs][1] = *(const bf16x8*)((const char*)Pw[wave] + prr * 128 + ((64 + g * 16) ^ ((ln & 7) << 4)));
    }
#pragma unroll
    for (int ns = 0; ns < 4; ++ns) {
      int vr = ns * 16 + ln;
      bf16x8 vb0 = *(const bf16x8*)((const char*)Vt[cur] + vr * 128 + ((g * 16) ^ VSWZ(vr)));
      bf16x8 vb1 = *(const bf16x8*)((const char*)Vt[cur] + vr * 128 + ((64 + g * 16) ^ VSWZ(vr)));
#pragma unroll
      for (int qs = 0; qs < 2; ++qs) {
        const int s0q = t * 128 + wave * 32 + qs * 16;
        if (kt * 64 > s0q + 15) continue;
        acc[qs][ns] = __builtin_amdgcn_mfma_f32_16x16x32_bf16(pa[qs][0], vb0, acc[qs][ns], 0, 0, 0);
        acc[qs][ns] = __builtin_amdgcn_mfma_f32_16x16x32_bf16(pa[qs][1], vb1, acc[qs][ns], 0, 0, 0);
      }
    }

    if (more) {
#pragma unroll
      for (int j = 0; j < 8; ++j) {
        int c = vc0 + j;
        unsigned int pack = (unsigned int)(u16)nr0[j] | ((unsigned int)(u16)nr1[j] << 16);
        *(unsigned int*)((char*)Vt[nxt] + c * 128 + ((vr0 * 2) ^ VSWZ(c))) = pack;
      }
    }
    __syncthreads();
  }

  // write unnormalized bf16 partial ctx + stats (exp2-domain m, l)
  const size_t slot = ((size_t)(b * NH + h)) * NPART_BH + p;
#pragma unroll
  for (int qs = 0; qs < 2; ++qs)
#pragma unroll
    for (int ns = 0; ns < 4; ++ns)
#pragma unroll
      for (int r = 0; r < 4; ++r) {
        int qr = wave * 32 + qs * 16 + g * 4 + r;
        CTXP[slot * 8192 + (size_t)qr * 64 + ns * 16 + ln] = f2bf(acc[qs][ns][r]);
      }
  if (ln == 0) {
#pragma unroll
    for (int qs = 0; qs < 2; ++qs)
#pragma unroll
      for (int r = 0; r < 4; ++r) {
        int qr = wave * 32 + qs * 16 + g * 4 + r;
        MP[slot * 128 + qr] = m_run[qs][r];
        LP[slot * 128 + qr] = l_run[qs][r];
      }
  }
}

// Merge K-chunk partials + fold L=4 memory slots (exp2 domain), final bf16 ctx.
__global__ __launch_bounds__(256)
void finalize(const u16* __restrict__ Q, const float* __restrict__ PQ,
              const float* __restrict__ PV, const u16* __restrict__ CTXP,
              const float* __restrict__ MP, const float* __restrict__ LP,
              u16* __restrict__ Cout) {
  const int lane = threadIdx.x & 63, wave = threadIdx.x >> 6;
  const size_t row = (size_t)blockIdx.x * 4 + wave;  // (b*H+h)*S + s
  const int s = (int)(row & (S_LEN - 1));
  const int h = (int)((row >> 11) & (NH - 1));
  const int b = (int)(row >> 15);

  const int t = s >> 7;
  int p0, parts;
  if (t < 4)       { p0 = t;                parts = 1; }
  else if (t < 8)  { p0 = 4 + (t - 4) * 2;  parts = 2; }
  else if (t < 12) { p0 = 12 + (t - 8) * 3; parts = 3; }
  else             { p0 = 24 + (t - 12) * 4; parts = 4; }
  const size_t slot0 = ((size_t)(b * NH + h)) * NPART_BH + p0;
  const int sr = s & 127;

  float mc[4], lc[4];
  float m_tok = -INFINITY;
#pragma unroll
  for (int c = 0; c < 4; ++c)
    if (c < parts) {
      mc[c] = MP[(slot0 + c) * 128 + sr];
      lc[c] = LP[(slot0 + c) * 128 + sr];
      m_tok = fmaxf(m_tok, mc[c]);
    }
  float l_tok = 0.f, cd = 0.f;
#pragma unroll
  for (int c = 0; c < 4; ++c)
    if (c < parts) {
      float w = exp2f(mc[c] - m_tok);
      l_tok += w * lc[c];
      cd += w * bf2f(CTXP[(slot0 + c) * 8192 + (size_t)sr * 64 + lane]);
    }

  // memory slots (log2-domain scores)
  const float qd = bf2f(Q[((size_t)b * S_LEN + s) * DIM + h * 64 + lane]);
  const float* pq = PQ + row * (NL * 64);
  const float* pv = PV + row * (NL * 64);
  float msc[NL];
  float m_fin = m_tok;
#pragma unroll
  for (int lm = 0; lm < NL; ++lm) {
    float prod = qd * pq[lm * 64 + lane];
#pragma unroll
    for (int o = 1; o < 64; o <<= 1) prod += __shfl_xor(prod, o);
    msc[lm] = prod * SCALE2;
    m_fin = fmaxf(m_fin, msc[lm]);
  }
  const float a = exp2f(m_tok - m_fin);
  float l_fin = l_tok * a;
  cd *= a;
#pragma unroll
  for (int lm = 0; lm < NL; ++lm) {
    float w = exp2f(msc[lm] - m_fin);
    l_fin += w;
    cd += w * pv[lm * 64 + lane];
  }
  Cout[((size_t)b * S_LEN + s) * DIM + h * 64 + lane] = f2bf(cd / l_fin);
}

extern "C" void kernel_launch(void* const* d_in, const int* in_sizes, int n_in,
                              void* d_out, int out_size, void* d_ws, size_t ws_size,
                              hipStream_t stream) {
  const float* x  = (const float*)d_in[0];
  const float* pq = (const float*)d_in[1];
  const float* pv = (const float*)d_in[2];
  const float* Wq = (const float*)d_in[3];
  const float* bq = (const float*)d_in[4];
  const float* Wo = (const float*)d_in[5];
  const float* bo = (const float*)d_in[6];
  float* out = (float*)d_out;

  const int M = NB * S_LEN;  // 4096
  u16*   Qws  = (u16*)d_ws;                    // 8 MB
  u16*   Cws  = Qws + (size_t)M * DIM;         // 8 MB
  u16*   xbf  = Cws + (size_t)M * DIM;         // 8 MB
  u16*   Wqbf = xbf + (size_t)M * DIM;         // 2 MB
  u16*   Wobf = Wqbf + (size_t)DIM * DIM;      // 2 MB
  u16*   CTXP = Wobf + (size_t)DIM * DIM;      // 1280 slots x 8192 bf16 = 21 MB
  float* MP   = (float*)(CTXP + (size_t)NB * NH * NPART_BH * 8192);  // 640 KB
  float* LP   = MP + (size_t)NB * NH * NPART_BH * 128;               // 640 KB

  const int n4x = M * DIM / 4, n4w = DIM * DIM / 4;
  cvt_f32_bf16<<<(n4x + 255) / 256, 256, 0, stream>>>(x, xbf, n4x);
  cvt_f32_bf16<<<(n4w + 255) / 256, 256, 0, stream>>>(Wq, Wqbf, n4w);
  cvt_f32_bf16<<<(n4w + 255) / 256, 256, 0, stream>>>(Wo, Wobf, n4w);

  gemm_bt<false, u16><<<dim3(DIM / 128, M / 128), 256, 0, stream>>>(
      xbf, Wqbf, bq, Qws, M, DIM, DIM);
  attn<<<dim3(NPART_BH, NH, NB), 256, 0, stream>>>(Qws, xbf, CTXP, MP, LP);
  finalize<<<NB * NH * S_LEN / 4, 256, 0, stream>>>(Qws, pq, pv, CTXP, MP, LP, Cws);
  gemm_bt<true, float><<<dim3(DIM / 128, M / 128), 256, 0, stream>>>(
      Cws, Wobf, bo, out, M, DIM, DIM);
}

// Round 5
// 154.075 us; speedup vs baseline: 1.1743x; 1.1743x over previous
//
#include <hip/hip_runtime.h>
#include <hip/hip_bf16.h>
#include <math.h>

#define S_LEN 2048
#define DIM   1024
#define NH    16
#define NL    4
#define NB    2
#define PARTS_PER_BH 80   // sum over 32 q-tiles(64) of ceil((qt+1)/8)
#define ALPHA 0.42466086f // sqrt(0.125 * log2(e)); folded into Q

typedef __attribute__((ext_vector_type(8))) short bf16x8;
typedef __attribute__((ext_vector_type(4))) float f32x4;
typedef unsigned short u16;

__device__ __forceinline__ float bf2f(u16 u) {
  union { unsigned int i; float f; } x; x.i = ((unsigned int)u) << 16; return x.f;
}
__device__ __forceinline__ u16 f2bf(float f) {  // RNE, integer path
  union { float f; unsigned int i; } x; x.f = f;
  unsigned int r = x.i + 0x7fffu + ((x.i >> 16) & 1u);
  return (u16)(r >> 16);
}
__device__ __forceinline__ u16 f2bfq(float f) { // compiler cvt path (v_cvt_pk_bf16_f32)
  __hip_bfloat16 h = __float2bfloat16(f);
  return *reinterpret_cast<u16*>(&h);
}

__device__ __forceinline__ void g2l16(const void* g, void* l) {
  __builtin_amdgcn_global_load_lds(
      (const __attribute__((address_space(1))) void*)g,
      (__attribute__((address_space(3))) void*)l, 16, 0, 0);
}

// DPP 16-lane butterfly reduce (VALU-speed).
template <int CTRL>
__device__ __forceinline__ float dppf(float x) {
  union { float f; int i; } u, r;
  u.f = x;
  r.i = __builtin_amdgcn_update_dpp(0, u.i, CTRL, 0xF, 0xF, true);
  return r.f;
}
__device__ __forceinline__ float rmax16(float x) {
  x = fmaxf(x, dppf<0xB1>(x));
  x = fmaxf(x, dppf<0x4E>(x));
  x = fmaxf(x, dppf<0x141>(x));
  x = fmaxf(x, dppf<0x140>(x));
  return x;
}
__device__ __forceinline__ float rsum16(float x) {
  x += dppf<0xB1>(x);
  x += dppf<0x4E>(x);
  x += dppf<0x141>(x);
  x += dppf<0x140>(x);
  return x;
}

// One fused f32->bf16 convert for x, Wq, Wo.
__global__ __launch_bounds__(256)
void cvt_all(const float* __restrict__ x, const float* __restrict__ wq,
             const float* __restrict__ wo, u16* __restrict__ ox,
             u16* __restrict__ owq, u16* __restrict__ owo, int n4x, int n4w) {
  int i = blockIdx.x * blockDim.x + threadIdx.x;
  const float* src; u16* dst; int j;
  if (i < n4x)            { src = x;  dst = ox;  j = i; }
  else if (i < n4x + n4w) { src = wq; dst = owq; j = i - n4x; }
  else                    { src = wo; dst = owo; j = i - n4x - n4w;
                            if (j >= n4w) return; }
  float4 v = ((const float4*)src)[j];
  ushort4 o;
  o.x = f2bf(v.x); o.y = f2bf(v.y); o.z = f2bf(v.z); o.w = f2bf(v.w);
  ((ushort4*)dst)[j] = o;
}

// C = act(A @ Bt^T + bias) * oscale. 128x64 tile, BK=64, 4 waves (2x2),
// wave = 64x32 out via 4x2 MFMA 16x16x32. 512 blocks -> 2 blocks/CU.
template <bool GELU, typename OT>
__global__ __launch_bounds__(256)
void gemm_bt(const u16* __restrict__ A, const u16* __restrict__ Bt,
             const float* __restrict__ bias, OT* __restrict__ C,
             int M, int N, int K, float oscale) {
  __shared__ u16 As[128 * 64];
  __shared__ u16 Bs[64 * 64];
  const int lane = threadIdx.x & 63, wave = threadIdx.x >> 6;
  const int ln = lane & 15, g = lane >> 4;
  const int m0 = blockIdx.y * 128, n0 = blockIdx.x * 64;
  const int wm = wave >> 1, wn = wave & 1;
  f32x4 acc[4][2] = {};

  for (int k0 = 0; k0 < K; k0 += 64) {
    __syncthreads();
#pragma unroll
    for (int rd = 0; rd < 6; ++rd) {
      int ch = rd * 4 + wave;                   // 0..23: 16 A-chunks + 8 B-chunks
      if (ch < 16) {
        int flat = ch * 1024 + lane * 16;
        int row = flat >> 7;
        int within = (flat & 127) ^ ((row & 7) << 4);
        g2l16((const char*)A + ((size_t)(m0 + row) * K + k0) * 2 + within,
              (char*)As + ch * 1024);
      } else {
        int flat = (ch - 16) * 1024 + lane * 16;
        int row = flat >> 7;
        int within = (flat & 127) ^ ((row & 7) << 4);
        g2l16((const char*)Bt + ((size_t)(n0 + row) * K + k0) * 2 + within,
              (char*)Bs + (ch - 16) * 1024);
      }
    }
    __syncthreads();
#pragma unroll
    for (int kc = 0; kc < 2; ++kc) {
      bf16x8 af[4], bfr[2];
#pragma unroll
      for (int i = 0; i < 4; ++i) {
        int ra = wm * 64 + i * 16 + ln;
        af[i] = *(const bf16x8*)((const char*)As + ra * 128 +
                                 ((kc * 64 + g * 16) ^ ((ra & 7) << 4)));
      }
#pragma unroll
      for (int j = 0; j < 2; ++j) {
        int rb = wn * 32 + j * 16 + ln;
        bfr[j] = *(const bf16x8*)((const char*)Bs + rb * 128 +
                                  ((kc * 64 + g * 16) ^ ((rb & 7) << 4)));
      }
#pragma unroll
      for (int i = 0; i < 4; ++i)
#pragma unroll
        for (int j = 0; j < 2; ++j)
          acc[i][j] = __builtin_amdgcn_mfma_f32_16x16x32_bf16(af[i], bfr[j], acc[i][j], 0, 0, 0);
    }
  }

#pragma unroll
  for (int j = 0; j < 2; ++j) {
    int gc = n0 + wn * 32 + j * 16 + ln;
    float bv = bias[gc];
#pragma unroll
    for (int i = 0; i < 4; ++i) {
      int gr0 = m0 + wm * 64 + i * 16 + g * 4;
#pragma unroll
      for (int r = 0; r < 4; ++r) {
        float v = acc[i][j][r] + bv;
        if constexpr (GELU) v = 0.5f * v * (1.0f + erff(v * 0.70710678118f));
        v *= oscale;
        if constexpr (sizeof(OT) == 2) C[(size_t)(gr0 + r) * N + gc] = (OT)f2bf(v);
        else                           C[(size_t)(gr0 + r) * N + gc] = (OT)v;
      }
    }
  }
}

// Flash self-attention, token part, K-chunked. QBLK=64 (4 waves x 16 q-rows),
// double-buffered, conflict-free swizzles, exp2 domain (scale pre-folded into
// Q), defer-rescale, bf16 partials. grid (PARTS_PER_BH, H, B).
__global__ __launch_bounds__(256)
void attn(const u16* __restrict__ Q, const u16* __restrict__ Xb,
          u16* __restrict__ CTXP, float* __restrict__ MP, float* __restrict__ LP) {
  __shared__ u16 Ks[2][64 * 64];
  __shared__ u16 Vt[2][64 * 64];
  __shared__ u16 Pw[4][16 * 64];

  const int lane = threadIdx.x & 63, wave = threadIdx.x >> 6;
  const int ln = lane & 15, g = lane >> 4;
  const int h = blockIdx.y, b = blockIdx.z;

  // part -> (qt, chunk); parts(qt) = ceil((qt+1)/8)
  const int p = blockIdx.x;
  int qt, chunk;
  if (p < 8)       { qt = p;                          chunk = 0; }
  else if (p < 24) { int i = p - 8;  qt = 8 + (i >> 1);  chunk = i & 1; }
  else if (p < 48) { int i = p - 24; qt = 16 + i / 3;    chunk = i % 3; }
  else             { int i = p - 48; qt = 24 + (i >> 2); chunk = i & 3; }
  const int kt0 = chunk * 8;
  const int kt1e = kt0 + 8 < qt + 1 ? kt0 + 8 : qt + 1;

  const size_t qrow = (size_t)b * S_LEN + qt * 64 + wave * 16 + ln;
  const bf16x8 qa0 = *(const bf16x8*)(Q + qrow * DIM + h * 64 + g * 8);
  const bf16x8 qa1 = *(const bf16x8*)(Q + qrow * DIM + h * 64 + 32 + g * 8);

  f32x4 acc[4] = {};
  float m_run[4] = {-INFINITY, -INFINITY, -INFINITY, -INFINITY};
  float l_run[4] = {0.f, 0.f, 0.f, 0.f};

  const int tid = threadIdx.x;
  const int vr0 = (tid >> 3) * 2;   // key row pair
  const int vc0 = (tid & 7) * 8;    // dim cols
  // conflict-free V^T swizzle (write & read side verified 2-way max)
#define VSWZ(c) ((((c) ^ ((c) >> 3)) & 7) << 4)

  // prologue: stage tile kt0 into buffer 0
  {
    const u16* xsrc = Xb + ((size_t)b * S_LEN + kt0 * 64 + vr0) * DIM + h * 64 + vc0;
    bf16x8 r0 = *(const bf16x8*)xsrc;
    bf16x8 r1 = *(const bf16x8*)(xsrc + DIM);
#pragma unroll
    for (int rd = 0; rd < 2; ++rd) {
      int ch = rd * 4 + wave;
      int flat = ch * 1024 + lane * 16;
      int row = flat >> 7;
      int within = (flat & 127) ^ ((row & 7) << 4);
      g2l16((const char*)Q + (((size_t)b * S_LEN + kt0 * 64 + row) * DIM + h * 64) * 2 + within,
            (char*)Ks[0] + ch * 1024);
    }
#pragma unroll
    for (int j = 0; j < 8; ++j) {
      int c = vc0 + j;
      unsigned int pack = (unsigned int)(u16)r0[j] | ((unsigned int)(u16)r1[j] << 16);
      *(unsigned int*)((char*)Vt[0] + c * 128 + ((vr0 * 2) ^ VSWZ(c))) = pack;
    }
  }
  __syncthreads();

  for (int kt = kt0; kt < kt1e; ++kt) {
    const int cur = (kt - kt0) & 1, nxt = cur ^ 1;
    const bool more = (kt + 1 < kt1e);
    bf16x8 nr0, nr1;
    if (more) {
      const u16* xsrc = Xb + ((size_t)b * S_LEN + (kt + 1) * 64 + vr0) * DIM + h * 64 + vc0;
      nr0 = *(const bf16x8*)xsrc;
      nr1 = *(const bf16x8*)(xsrc + DIM);
#pragma unroll
      for (int rd = 0; rd < 2; ++rd) {
        int ch = rd * 4 + wave;
        int flat = ch * 1024 + lane * 16;
        int row = flat >> 7;
        int within = (flat & 127) ^ ((row & 7) << 4);
        g2l16((const char*)Q + (((size_t)b * S_LEN + (kt + 1) * 64 + row) * DIM + h * 64) * 2 + within,
              (char*)Ks[nxt] + ch * 1024);
      }
      __builtin_amdgcn_sched_barrier(0);
    }

    // QK^T from Ks[cur]; scale already folded into Q
    float pv_[4][4];
#pragma unroll
    for (int sub = 0; sub < 4; ++sub) {
      int kr = sub * 16 + ln;
      bf16x8 kb0 = *(const bf16x8*)((const char*)Ks[cur] + kr * 128 + ((g * 16) ^ ((kr & 7) << 4)));
      bf16x8 kb1 = *(const bf16x8*)((const char*)Ks[cur] + kr * 128 + ((64 + g * 16) ^ ((kr & 7) << 4)));
      f32x4 c = {};
      c = __builtin_amdgcn_mfma_f32_16x16x32_bf16(qa0, kb0, c, 0, 0, 0);
      c = __builtin_amdgcn_mfma_f32_16x16x32_bf16(qa1, kb1, c, 0, 0, 0);
      if (kt == qt) {
#pragma unroll
        for (int r = 0; r < 4; ++r) {
          int key = sub * 16 + ln;
          int qi = wave * 16 + g * 4 + r;
          pv_[sub][r] = (key > qi) ? -INFINITY : c[r];
        }
      } else {
#pragma unroll
        for (int r = 0; r < 4; ++r) pv_[sub][r] = c[r];
      }
    }

    // online softmax (exp2 domain) with defer-rescale (THR=8)
    float nm[4];
    bool okl = true;
#pragma unroll
    for (int r = 0; r < 4; ++r) {
      nm[r] = rmax16(fmaxf(fmaxf(pv_[0][r], pv_[1][r]), fmaxf(pv_[2][r], pv_[3][r])));
      okl = okl && (nm[r] <= m_run[r] + 8.0f);
    }
    if (!__all(okl)) {
#pragma unroll
      for (int r = 0; r < 4; ++r) {
        float mnew = fmaxf(m_run[r], nm[r]);
        float scl = exp2f(m_run[r] - mnew);
        m_run[r] = mnew;
        l_run[r] *= scl;
#pragma unroll
        for (int ns = 0; ns < 4; ++ns) acc[ns][r] *= scl;
      }
    }
#pragma unroll
    for (int sub = 0; sub < 4; ++sub)
#pragma unroll
      for (int r = 0; r < 4; ++r) pv_[sub][r] = exp2f(pv_[sub][r] - m_run[r]);
#pragma unroll
    for (int r = 0; r < 4; ++r)
      l_run[r] += rsum16(pv_[0][r] + pv_[1][r] + pv_[2][r] + pv_[3][r]);

    // P: C-layout -> LDS (per-wave) -> A-layout
#pragma unroll
    for (int sub = 0; sub < 4; ++sub)
#pragma unroll
      for (int r = 0; r < 4; ++r) {
        int pr = g * 4 + r;
        *(u16*)((char*)Pw[wave] + pr * 128 + (((sub * 16 + ln) * 2) ^ ((pr & 7) << 4))) =
            f2bfq(pv_[sub][r]);
      }
    bf16x8 pa0 = *(const bf16x8*)((const char*)Pw[wave] + ln * 128 + ((g * 16) ^ ((ln & 7) << 4)));
    bf16x8 pa1 = *(const bf16x8*)((const char*)Pw[wave] + ln * 128 + ((64 + g * 16) ^ ((ln & 7) << 4)));
#pragma unroll
    for (int ns = 0; ns < 4; ++ns) {
      int vr = ns * 16 + ln;
      bf16x8 vb0 = *(const bf16x8*)((const char*)Vt[cur] + vr * 128 + ((g * 16) ^ VSWZ(vr)));
      bf16x8 vb1 = *(const bf16x8*)((const char*)Vt[cur] + vr * 128 + ((64 + g * 16) ^ VSWZ(vr)));
      acc[ns] = __builtin_amdgcn_mfma_f32_16x16x32_bf16(pa0, vb0, acc[ns], 0, 0, 0);
      acc[ns] = __builtin_amdgcn_mfma_f32_16x16x32_bf16(pa1, vb1, acc[ns], 0, 0, 0);
    }

    if (more) {
#pragma unroll
      for (int j = 0; j < 8; ++j) {
        int c = vc0 + j;
        unsigned int pack = (unsigned int)(u16)nr0[j] | ((unsigned int)(u16)nr1[j] << 16);
        *(unsigned int*)((char*)Vt[nxt] + c * 128 + ((vr0 * 2) ^ VSWZ(c))) = pack;
      }
    }
    __syncthreads();
  }

  // write unnormalized bf16 partial ctx + stats (log2-domain m, l)
  const size_t slot = ((size_t)(b * NH + h)) * PARTS_PER_BH + p;
#pragma unroll
  for (int ns = 0; ns < 4; ++ns)
#pragma unroll
    for (int r = 0; r < 4; ++r) {
      int qr = wave * 16 + g * 4 + r;
      CTXP[slot * 4096 + (size_t)qr * 64 + ns * 16 + ln] = f2bfq(acc[ns][r]);
    }
  if (ln == 0) {
#pragma unroll
    for (int r = 0; r < 4; ++r) {
      int qr = wave * 16 + g * 4 + r;
      MP[slot * 64 + qr] = m_run[r];
      LP[slot * 64 + qr] = l_run[r];
    }
  }
}

// Merge K-chunk partials + fold L=4 memory slots (log2 domain), final bf16 ctx.
__global__ __launch_bounds__(256)
void finalize(const u16* __restrict__ Q, const float* __restrict__ PQ,
              const float* __restrict__ PV, const u16* __restrict__ CTXP,
              const float* __restrict__ MP, const float* __restrict__ LP,
              u16* __restrict__ Cout) {
  const int lane = threadIdx.x & 63, wave = threadIdx.x >> 6;
  const size_t row = (size_t)blockIdx.x * 4 + wave;  // (b*H+h)*S + s
  const int s = (int)(row & (S_LEN - 1));
  const int h = (int)((row >> 11) & (NH - 1));
  const int b = (int)(row >> 15);

  const int qt = s >> 6, G = qt >> 3, parts = G + 1;
  const int baseG[4] = {0, 8, 24, 48};
  const int p0 = baseG[G] + (qt & 7) * parts;
  const size_t slot0 = ((size_t)(b * NH + h)) * PARTS_PER_BH + p0;
  const int sr = s & 63;

  float mc[4], lc[4];
  float m_tok = -INFINITY;
#pragma unroll
  for (int c = 0; c < 4; ++c)
    if (c < parts) {
      mc[c] = MP[(slot0 + c) * 64 + sr];
      lc[c] = LP[(slot0 + c) * 64 + sr];
      m_tok = fmaxf(m_tok, mc[c]);
    }
  float l_tok = 0.f, cd = 0.f;
#pragma unroll
  for (int c = 0; c < 4; ++c)
    if (c < parts) {
      float w = exp2f(mc[c] - m_tok);
      l_tok += w * lc[c];
      cd += w * bf2f(CTXP[(slot0 + c) * 4096 + (size_t)sr * 64 + lane]);
    }

  // memory slots (qd carries one ALPHA; multiply by ALPHA for full scale)
  const float qd = bf2f(Q[((size_t)b * S_LEN + s) * DIM + h * 64 + lane]);
  const float* pq = PQ + row * (NL * 64);
  const float* pv = PV + row * (NL * 64);
  float msc[NL];
  float m_fin = m_tok;
#pragma unroll
  for (int lm = 0; lm < NL; ++lm) {
    float prod = qd * pq[lm * 64 + lane];
#pragma unroll
    for (int o = 1; o < 64; o <<= 1) prod += __shfl_xor(prod, o);
    msc[lm] = prod * ALPHA;
    m_fin = fmaxf(m_fin, msc[lm]);
  }
  const float a = exp2f(m_tok - m_fin);
  float l_fin = l_tok * a;
  cd *= a;
#pragma unroll
  for (int lm = 0; lm < NL; ++lm) {
    float w = exp2f(msc[lm] - m_fin);
    l_fin += w;
    cd += w * pv[lm * 64 + lane];
  }
  Cout[((size_t)b * S_LEN + s) * DIM + h * 64 + lane] = f2bf(cd / l_fin);
}

extern "C" void kernel_launch(void* const* d_in, const int* in_sizes, int n_in,
                              void* d_out, int out_size, void* d_ws, size_t ws_size,
                              hipStream_t stream) {
  const float* x  = (const float*)d_in[0];
  const float* pq = (const float*)d_in[1];
  const float* pv = (const float*)d_in[2];
  const float* Wq = (const float*)d_in[3];
  const float* bq = (const float*)d_in[4];
  const float* Wo = (const float*)d_in[5];
  const float* bo = (const float*)d_in[6];
  float* out = (float*)d_out;

  const int M = NB * S_LEN;  // 4096
  u16*   Qws  = (u16*)d_ws;                    // 8 MB (ALPHA-scaled Q, bf16)
  u16*   Cws  = Qws + (size_t)M * DIM;         // 8 MB
  u16*   xbf  = Cws + (size_t)M * DIM;         // 8 MB
  u16*   Wqbf = xbf + (size_t)M * DIM;         // 2 MB
  u16*   Wobf = Wqbf + (size_t)DIM * DIM;      // 2 MB
  u16*   CTXP = Wobf + (size_t)DIM * DIM;      // 2560 slots x 4096 bf16 = 21 MB
  float* MP   = (float*)(CTXP + (size_t)NB * NH * PARTS_PER_BH * 4096);  // 640 KB
  float* LP   = MP + (size_t)NB * NH * PARTS_PER_BH * 64;                // 640 KB

  const int n4x = M * DIM / 4, n4w = DIM * DIM / 4;
  cvt_all<<<(n4x + 2 * n4w + 255) / 256, 256, 0, stream>>>(
      x, Wq, Wo, xbf, Wqbf, Wobf, n4x, n4w);

  gemm_bt<false, u16><<<dim3(DIM / 64, M / 128), 256, 0, stream>>>(
      xbf, Wqbf, bq, Qws, M, DIM, DIM, ALPHA);
  attn<<<dim3(PARTS_PER_BH, NH, NB), 256, 0, stream>>>(Qws, xbf, CTXP, MP, LP);
  finalize<<<NB * NH * S_LEN / 4, 256, 0, stream>>>(Qws, pq, pv, CTXP, MP, LP, Cws);
  gemm_bt<true, float><<<dim3(DIM / 64, M / 128), 256, 0, stream>>>(
      Cws, Wobf, bo, out, M, DIM, DIM, 1.0f);
}

// Round 6
// 137.798 us; speedup vs baseline: 1.3130x; 1.1181x over previous
//
#include <hip/hip_runtime.h>
#include <hip/hip_bf16.h>
#include <math.h>

#define S_LEN 2048
#define DIM   1024
#define NH    16
#define NL    4
#define NB    2
#define PARTS_PER_BH 80   // sum over 32 q-tiles(64) of ceil((qt+1)/8)
#define ALPHA 0.42466086f // sqrt(0.125 * log2(e)); folded into Q

typedef __attribute__((ext_vector_type(8))) short bf16x8;
typedef __attribute__((ext_vector_type(4))) float f32x4;
typedef unsigned short u16;

__device__ __forceinline__ float bf2f(u16 u) {
  union { unsigned int i; float f; } x; x.i = ((unsigned int)u) << 16; return x.f;
}
__device__ __forceinline__ u16 f2bf(float f) {  // RNE, integer path
  union { float f; unsigned int i; } x; x.f = f;
  unsigned int r = x.i + 0x7fffu + ((x.i >> 16) & 1u);
  return (u16)(r >> 16);
}
__device__ __forceinline__ u16 f2bfq(float f) { // compiler cvt path
  __hip_bfloat16 h = __float2bfloat16(f);
  return *reinterpret_cast<u16*>(&h);
}

__device__ __forceinline__ void g2l16(const void* g, void* l) {
  __builtin_amdgcn_global_load_lds(
      (const __attribute__((address_space(1))) void*)g,
      (__attribute__((address_space(3))) void*)l, 16, 0, 0);
}

// One fused f32->bf16 convert for x, Wq, Wo.
__global__ __launch_bounds__(256)
void cvt_all(const float* __restrict__ x, const float* __restrict__ wq,
             const float* __restrict__ wo, u16* __restrict__ ox,
             u16* __restrict__ owq, u16* __restrict__ owo, int n4x, int n4w) {
  int i = blockIdx.x * blockDim.x + threadIdx.x;
  const float* src; u16* dst; int j;
  if (i < n4x)            { src = x;  dst = ox;  j = i; }
  else if (i < n4x + n4w) { src = wq; dst = owq; j = i - n4x; }
  else                    { src = wo; dst = owo; j = i - n4x - n4w;
                            if (j >= n4w) return; }
  float4 v = ((const float4*)src)[j];
  ushort4 o;
  o.x = f2bf(v.x); o.y = f2bf(v.y); o.z = f2bf(v.z); o.w = f2bf(v.w);
  ((ushort4*)dst)[j] = o;
}

// C = act(A @ Bt^T + bias) * oscale. 128x64 tile, BK=64, 4 waves (2x2),
// wave = 64x32 out via 4x2 MFMA 16x16x32. 512 blocks -> 2 blocks/CU.
template <bool GELU, typename OT>
__global__ __launch_bounds__(256)
void gemm_bt(const u16* __restrict__ A, const u16* __restrict__ Bt,
             const float* __restrict__ bias, OT* __restrict__ C,
             int M, int N, int K, float oscale) {
  __shared__ u16 As[128 * 64];
  __shared__ u16 Bs[64 * 64];
  const int lane = threadIdx.x & 63, wave = threadIdx.x >> 6;
  const int ln = lane & 15, g = lane >> 4;
  const int m0 = blockIdx.y * 128, n0 = blockIdx.x * 64;
  const int wm = wave >> 1, wn = wave & 1;
  f32x4 acc[4][2] = {};

  for (int k0 = 0; k0 < K; k0 += 64) {
    __syncthreads();
#pragma unroll
    for (int rd = 0; rd < 6; ++rd) {
      int ch = rd * 4 + wave;                   // 0..23: 16 A-chunks + 8 B-chunks
      if (ch < 16) {
        int flat = ch * 1024 + lane * 16;
        int row = flat >> 7;
        int within = (flat & 127) ^ ((row & 7) << 4);
        g2l16((const char*)A + ((size_t)(m0 + row) * K + k0) * 2 + within,
              (char*)As + ch * 1024);
      } else {
        int flat = (ch - 16) * 1024 + lane * 16;
        int row = flat >> 7;
        int within = (flat & 127) ^ ((row & 7) << 4);
        g2l16((const char*)Bt + ((size_t)(n0 + row) * K + k0) * 2 + within,
              (char*)Bs + (ch - 16) * 1024);
      }
    }
    __syncthreads();
#pragma unroll
    for (int kc = 0; kc < 2; ++kc) {
      bf16x8 af[4], bfr[2];
#pragma unroll
      for (int i = 0; i < 4; ++i) {
        int ra = wm * 64 + i * 16 + ln;
        af[i] = *(const bf16x8*)((const char*)As + ra * 128 +
                                 ((kc * 64 + g * 16) ^ ((ra & 7) << 4)));
      }
#pragma unroll
      for (int j = 0; j < 2; ++j) {
        int rb = wn * 32 + j * 16 + ln;
        bfr[j] = *(const bf16x8*)((const char*)Bs + rb * 128 +
                                  ((kc * 64 + g * 16) ^ ((rb & 7) << 4)));
      }
#pragma unroll
      for (int i = 0; i < 4; ++i)
#pragma unroll
        for (int j = 0; j < 2; ++j)
          acc[i][j] = __builtin_amdgcn_mfma_f32_16x16x32_bf16(af[i], bfr[j], acc[i][j], 0, 0, 0);
    }
  }

#pragma unroll
  for (int j = 0; j < 2; ++j) {
    int gc = n0 + wn * 32 + j * 16 + ln;
    float bv = bias[gc];
#pragma unroll
    for (int i = 0; i < 4; ++i) {
      int gr0 = m0 + wm * 64 + i * 16 + g * 4;
#pragma unroll
      for (int r = 0; r < 4; ++r) {
        float v = acc[i][j][r] + bv;
        if constexpr (GELU) v = 0.5f * v * (1.0f + erff(v * 0.70710678118f));
        v *= oscale;
        if constexpr (sizeof(OT) == 2) C[(size_t)(gr0 + r) * N + gc] = (OT)f2bf(v);
        else                           C[(size_t)(gr0 + r) * N + gc] = (OT)v;
      }
    }
  }
}

// Flash self-attention, token part, K-chunked. QBLK=64 (4 waves x 16 q-rows).
// SWAPPED QK^T: mfma(K,Q) -> D[key][q], q = ln lane-local => in-lane softmax
// rows, scalar m/l state, packed b64 P-stores. grid (PARTS_PER_BH, H, B).
__global__ __launch_bounds__(256)
void attn(const u16* __restrict__ Q, const u16* __restrict__ Xb,
          u16* __restrict__ CTXP, float* __restrict__ MP, float* __restrict__ LP) {
  __shared__ u16 Ks[2][64 * 64];
  __shared__ u16 Vt[2][64 * 64];
  __shared__ u16 Pw[4][16 * 64];

  const int lane = threadIdx.x & 63, wave = threadIdx.x >> 6;
  const int ln = lane & 15, g = lane >> 4;
  const int h = blockIdx.y, b = blockIdx.z;

  // part -> (qt, chunk); parts(qt) = ceil((qt+1)/8)
  const int p = blockIdx.x;
  int qt, chunk;
  if (p < 8)       { qt = p;                          chunk = 0; }
  else if (p < 24) { int i = p - 8;  qt = 8 + (i >> 1);  chunk = i & 1; }
  else if (p < 48) { int i = p - 24; qt = 16 + i / 3;    chunk = i % 3; }
  else             { int i = p - 48; qt = 24 + (i >> 2); chunk = i & 3; }
  const int kt0 = chunk * 8;
  const int kt1e = kt0 + 8 < qt + 1 ? kt0 + 8 : qt + 1;

  const size_t qrow = (size_t)b * S_LEN + qt * 64 + wave * 16 + ln;
  const bf16x8 qa0 = *(const bf16x8*)(Q + qrow * DIM + h * 64 + g * 8);
  const bf16x8 qa1 = *(const bf16x8*)(Q + qrow * DIM + h * 64 + 32 + g * 8);

  f32x4 acc[4] = {};
  float m_run = -INFINITY;   // per-lane: q = ln (replicated across g)
  float l_run = 0.f;

  const int tid = threadIdx.x;
  const int vr0 = (tid >> 3) * 2;   // key row pair
  const int vc0 = (tid & 7) * 8;    // dim cols
#define VSWZ(c) ((((c) ^ ((c) >> 3)) & 7) << 4)

  // prologue: stage tile kt0 into buffer 0
  {
    const u16* xsrc = Xb + ((size_t)b * S_LEN + kt0 * 64 + vr0) * DIM + h * 64 + vc0;
    bf16x8 r0 = *(const bf16x8*)xsrc;
    bf16x8 r1 = *(const bf16x8*)(xsrc + DIM);
#pragma unroll
    for (int rd = 0; rd < 2; ++rd) {
      int ch = rd * 4 + wave;
      int flat = ch * 1024 + lane * 16;
      int row = flat >> 7;
      int within = (flat & 127) ^ ((row & 7) << 4);
      g2l16((const char*)Q + (((size_t)b * S_LEN + kt0 * 64 + row) * DIM + h * 64) * 2 + within,
            (char*)Ks[0] + ch * 1024);
    }
#pragma unroll
    for (int j = 0; j < 8; ++j) {
      int c = vc0 + j;
      unsigned int pack = (unsigned int)(u16)r0[j] | ((unsigned int)(u16)r1[j] << 16);
      *(unsigned int*)((char*)Vt[0] + c * 128 + ((vr0 * 2) ^ VSWZ(c))) = pack;
    }
  }
  __syncthreads();

  for (int kt = kt0; kt < kt1e; ++kt) {
    const int cur = (kt - kt0) & 1, nxt = cur ^ 1;
    const bool more = (kt + 1 < kt1e);
    bf16x8 nr0, nr1;
    if (more) {
      const u16* xsrc = Xb + ((size_t)b * S_LEN + (kt + 1) * 64 + vr0) * DIM + h * 64 + vc0;
      nr0 = *(const bf16x8*)xsrc;
      nr1 = *(const bf16x8*)(xsrc + DIM);
#pragma unroll
      for (int rd = 0; rd < 2; ++rd) {
        int ch = rd * 4 + wave;
        int flat = ch * 1024 + lane * 16;
        int row = flat >> 7;
        int within = (flat & 127) ^ ((row & 7) << 4);
        g2l16((const char*)Q + (((size_t)b * S_LEN + (kt + 1) * 64 + row) * DIM + h * 64) * 2 + within,
              (char*)Ks[nxt] + ch * 1024);
      }
      __builtin_amdgcn_sched_barrier(0);
    }

    // QK^T SWAPPED: D[key][q]; lane holds key = sub*16 + g*4 + r, q = ln
    float pv_[4][4];
#pragma unroll
    for (int sub = 0; sub < 4; ++sub) {
      int kr = sub * 16 + ln;
      bf16x8 kb0 = *(const bf16x8*)((const char*)Ks[cur] + kr * 128 + ((g * 16) ^ ((kr & 7) << 4)));
      bf16x8 kb1 = *(const bf16x8*)((const char*)Ks[cur] + kr * 128 + ((64 + g * 16) ^ ((kr & 7) << 4)));
      f32x4 c = {};
      c = __builtin_amdgcn_mfma_f32_16x16x32_bf16(kb0, qa0, c, 0, 0, 0);
      c = __builtin_amdgcn_mfma_f32_16x16x32_bf16(kb1, qa1, c, 0, 0, 0);
      if (kt == qt) {
#pragma unroll
        for (int r = 0; r < 4; ++r) {
          int key = sub * 16 + g * 4 + r;
          int qi = wave * 16 + ln;
          pv_[sub][r] = (key > qi) ? -INFINITY : c[r];
        }
      } else {
#pragma unroll
        for (int r = 0; r < 4; ++r) pv_[sub][r] = c[r];
      }
    }

    // in-lane row max over this lane's 16 scores, then cross-g butterfly
    float pmax = pv_[0][0];
#pragma unroll
    for (int sub = 0; sub < 4; ++sub)
#pragma unroll
      for (int r = 0; r < 4; ++r) pmax = fmaxf(pmax, pv_[sub][r]);
    pmax = fmaxf(pmax, __shfl_xor(pmax, 16));
    pmax = fmaxf(pmax, __shfl_xor(pmax, 32));

    // defer-rescale (THR=8, log2 domain)
    if (!__all(pmax <= m_run + 8.0f)) {
      float m_new = fmaxf(m_run, pmax);
      float scl = exp2f(m_run - m_new);
      m_run = m_new;
      l_run *= scl;
      // acc rows are q = g*4+r: fetch that q's scl
#pragma unroll
      for (int r = 0; r < 4; ++r) {
        float s = __shfl(scl, g * 4 + r);
#pragma unroll
        for (int ns = 0; ns < 4; ++ns) acc[ns][r] *= s;
      }
    }

    float lsum = 0.f;
#pragma unroll
    for (int sub = 0; sub < 4; ++sub)
#pragma unroll
      for (int r = 0; r < 4; ++r) {
        pv_[sub][r] = exp2f(pv_[sub][r] - m_run);
        lsum += pv_[sub][r];
      }
    lsum += __shfl_xor(lsum, 16);
    lsum += __shfl_xor(lsum, 32);
    l_run += lsum;

    // P store: 4 key-consecutive bf16 per (lane,sub) -> one b64 each
#pragma unroll
    for (int sub = 0; sub < 4; ++sub) {
      uint2 val;
      val.x = (unsigned int)f2bfq(pv_[sub][0]) | ((unsigned int)f2bfq(pv_[sub][1]) << 16);
      val.y = (unsigned int)f2bfq(pv_[sub][2]) | ((unsigned int)f2bfq(pv_[sub][3]) << 16);
      *(uint2*)((char*)Pw[wave] + ln * 128 + ((sub * 32 + g * 8) ^ ((ln & 7) << 4))) = val;
    }

    bf16x8 pa0 = *(const bf16x8*)((const char*)Pw[wave] + ln * 128 + ((g * 16) ^ ((ln & 7) << 4)));
    bf16x8 pa1 = *(const bf16x8*)((const char*)Pw[wave] + ln * 128 + ((64 + g * 16) ^ ((ln & 7) << 4)));
#pragma unroll
    for (int ns = 0; ns < 4; ++ns) {
      int vr = ns * 16 + ln;
      bf16x8 vb0 = *(const bf16x8*)((const char*)Vt[cur] + vr * 128 + ((g * 16) ^ VSWZ(vr)));
      bf16x8 vb1 = *(const bf16x8*)((const char*)Vt[cur] + vr * 128 + ((64 + g * 16) ^ VSWZ(vr)));
      acc[ns] = __builtin_amdgcn_mfma_f32_16x16x32_bf16(pa0, vb0, acc[ns], 0, 0, 0);
      acc[ns] = __builtin_amdgcn_mfma_f32_16x16x32_bf16(pa1, vb1, acc[ns], 0, 0, 0);
    }

    if (more) {
#pragma unroll
      for (int j = 0; j < 8; ++j) {
        int c = vc0 + j;
        unsigned int pack = (unsigned int)(u16)nr0[j] | ((unsigned int)(u16)nr1[j] << 16);
        *(unsigned int*)((char*)Vt[nxt] + c * 128 + ((vr0 * 2) ^ VSWZ(c))) = pack;
      }
    }
    __syncthreads();
  }

  // write unnormalized bf16 partial ctx + stats (log2-domain m, l)
  const size_t slot = ((size_t)(b * NH + h)) * PARTS_PER_BH + p;
#pragma unroll
  for (int ns = 0; ns < 4; ++ns)
#pragma unroll
    for (int r = 0; r < 4; ++r) {
      int qr = wave * 16 + g * 4 + r;
      CTXP[slot * 4096 + (size_t)qr * 64 + ns * 16 + ln] = f2bfq(acc[ns][r]);
    }
  if (lane < 16) {
    MP[slot * 64 + wave * 16 + lane] = m_run;
    LP[slot * 64 + wave * 16 + lane] = l_run;
  }
}

// Merge K-chunk partials + fold L=4 memory slots (log2 domain), final bf16 ctx.
__global__ __launch_bounds__(256)
void finalize(const u16* __restrict__ Q, const float* __restrict__ PQ,
              const float* __restrict__ PV, const u16* __restrict__ CTXP,
              const float* __restrict__ MP, const float* __restrict__ LP,
              u16* __restrict__ Cout) {
  const int lane = threadIdx.x & 63, wave = threadIdx.x >> 6;
  const size_t row = (size_t)blockIdx.x * 4 + wave;  // (b*H+h)*S + s
  const int s = (int)(row & (S_LEN - 1));
  const int h = (int)((row >> 11) & (NH - 1));
  const int b = (int)(row >> 15);

  const int qt = s >> 6, G = qt >> 3, parts = G + 1;
  const int baseG[4] = {0, 8, 24, 48};
  const int p0 = baseG[G] + (qt & 7) * parts;
  const size_t slot0 = ((size_t)(b * NH + h)) * PARTS_PER_BH + p0;
  const int sr = s & 63;

  float mc[4], lc[4];
  float m_tok = -INFINITY;
#pragma unroll
  for (int c = 0; c < 4; ++c)
    if (c < parts) {
      mc[c] = MP[(slot0 + c) * 64 + sr];
      lc[c] = LP[(slot0 + c) * 64 + sr];
      m_tok = fmaxf(m_tok, mc[c]);
    }
  float l_tok = 0.f, cd = 0.f;
#pragma unroll
  for (int c = 0; c < 4; ++c)
    if (c < parts) {
      float w = exp2f(mc[c] - m_tok);
      l_tok += w * lc[c];
      cd += w * bf2f(CTXP[(slot0 + c) * 4096 + (size_t)sr * 64 + lane]);
    }

  // memory slots (qd carries one ALPHA; multiply by ALPHA for full scale)
  const float qd = bf2f(Q[((size_t)b * S_LEN + s) * DIM + h * 64 + lane]);
  const float* pq = PQ + row * (NL * 64);
  const float* pv = PV + row * (NL * 64);
  float msc[NL];
  float m_fin = m_tok;
#pragma unroll
  for (int lm = 0; lm < NL; ++lm) {
    float prod = qd * pq[lm * 64 + lane];
#pragma unroll
    for (int o = 1; o < 64; o <<= 1) prod += __shfl_xor(prod, o);
    msc[lm] = prod * ALPHA;
    m_fin = fmaxf(m_fin, msc[lm]);
  }
  const float a = exp2f(m_tok - m_fin);
  float l_fin = l_tok * a;
  cd *= a;
#pragma unroll
  for (int lm = 0; lm < NL; ++lm) {
    float w = exp2f(msc[lm] - m_fin);
    l_fin += w;
    cd += w * pv[lm * 64 + lane];
  }
  Cout[((size_t)b * S_LEN + s) * DIM + h * 64 + lane] = f2bf(cd / l_fin);
}

extern "C" void kernel_launch(void* const* d_in, const int* in_sizes, int n_in,
                              void* d_out, int out_size, void* d_ws, size_t ws_size,
                              hipStream_t stream) {
  const float* x  = (const float*)d_in[0];
  const float* pq = (const float*)d_in[1];
  const float* pv = (const float*)d_in[2];
  const float* Wq = (const float*)d_in[3];
  const float* bq = (const float*)d_in[4];
  const float* Wo = (const float*)d_in[5];
  const float* bo = (const float*)d_in[6];
  float* out = (float*)d_out;

  const int M = NB * S_LEN;  // 4096
  u16*   Qws  = (u16*)d_ws;                    // 8 MB (ALPHA-scaled Q, bf16)
  u16*   Cws  = Qws + (size_t)M * DIM;         // 8 MB
  u16*   xbf  = Cws + (size_t)M * DIM;         // 8 MB
  u16*   Wqbf = xbf + (size_t)M * DIM;         // 2 MB
  u16*   Wobf = Wqbf + (size_t)DIM * DIM;      // 2 MB
  u16*   CTXP = Wobf + (size_t)DIM * DIM;      // 2560 slots x 4096 bf16 = 21 MB
  float* MP   = (float*)(CTXP + (size_t)NB * NH * PARTS_PER_BH * 4096);  // 640 KB
  float* LP   = MP + (size_t)NB * NH * PARTS_PER_BH * 64;                // 640 KB

  const int n4x = M * DIM / 4, n4w = DIM * DIM / 4;
  cvt_all<<<(n4x + 2 * n4w + 255) / 256, 256, 0, stream>>>(
      x, Wq, Wo, xbf, Wqbf, Wobf, n4x, n4w);

  gemm_bt<false, u16><<<dim3(DIM / 64, M / 128), 256, 0, stream>>>(
      xbf, Wqbf, bq, Qws, M, DIM, DIM, ALPHA);
  attn<<<dim3(PARTS_PER_BH, NH, NB), 256, 0, stream>>>(Qws, xbf, CTXP, MP, LP);
  finalize<<<NB * NH * S_LEN / 4, 256, 0, stream>>>(Qws, pq, pv, CTXP, MP, LP, Cws);
  gemm_bt<true, float><<<dim3(DIM / 64, M / 128), 256, 0, stream>>>(
      Cws, Wobf, bo, out, M, DIM, DIM, 1.0f);
}